// Round 14
// baseline (127.394 us; speedup 1.0000x reference)
//
#include <hip/hip_runtime.h>
#include <math.h>

// B=16,H=14,W=14,D=512, L=32, HID=512, A=512. fp32 in/out; bf16 inside MFMA GEMMs.
// R14: SINGLE kernel, 768 blocks x 256 threads, producer->consumer one-way flags:
//   blocks 0..255  : gemm1 tile (hlin = hiddens@W_hidden^T + b_hidden) -> flag1
//   blocks 256..511: mid (b,l-pair): poll flag1[b*16+*], scores+online softmax+ctx -> flag2
//   blocks 512..767: gemm2 tile: poll flag2[batch*16+*], (ctx@W_co^T + b_co)*hiddens
// Deadlock-free: all blocks <=64KB LDS -> any two fit in 160KB/CU -> blocks 0..511
// co-resident; gemm2 blocks fill slots as gemm1 retires. Flags in ws: 0xAA poison
// reads as negative int, epoch=1 -> no memset node. Polls are RELAXED (R10: acquire-
// per-poll costs ~55us); ONE acquire fence after the wait.

typedef __attribute__((ext_vector_type(8))) short short8;
typedef __attribute__((ext_vector_type(4))) float f32x4;

__device__ __forceinline__ unsigned f2bf_u(float x) {
    union { float f; unsigned u; } c; c.f = x;
    return (c.u + 0x7FFFu + ((c.u >> 16) & 1u)) >> 16;   // RNE, finite inputs
}
__device__ __forceinline__ unsigned pack2(float lo, float hi) {
    return f2bf_u(lo) | (f2bf_u(hi) << 16);
}
__device__ __forceinline__ uint4 pack8(const float4 a, const float4 b) {
    uint4 r;
    r.x = pack2(a.x, a.y); r.y = pack2(a.z, a.w);
    r.z = pack2(b.x, b.y); r.w = pack2(b.z, b.w);
    return r;
}

// wait for 16 flags (stride 16 ints = 64B) then acquire once. tid<16 poll.
__device__ __forceinline__ void wait16(const int* flags, int base) {
    if (threadIdx.x < 16) {
        while (__hip_atomic_load(&flags[(base + threadIdx.x) * 16],
                                 __ATOMIC_RELAXED, __HIP_MEMORY_SCOPE_AGENT) < 1)
            __builtin_amdgcn_s_sleep(1);
    }
    __syncthreads();
    __builtin_amdgcn_fence(__ATOMIC_ACQUIRE, "agent");
}

__device__ __forceinline__ void signal1(int* flags, int idx) {
    __syncthreads();                       // all stores of the block issued
    if (threadIdx.x == 0)
        __hip_atomic_store(&flags[idx * 16], 1, __ATOMIC_RELEASE, __HIP_MEMORY_SCOPE_AGENT);
}

// ---- GEMM body (R12-proven): C = A·B^T + bias[n] [* hmul]; 32x32 tile, bf16 MFMA ----
template<int MODE>
__device__ __forceinline__ void gemm_body(
    const float* __restrict__ Af, const unsigned short* __restrict__ Ab,
    const float* __restrict__ Bf, const float* __restrict__ bias,
    const float* __restrict__ hmul, float* __restrict__ C,
    char* smem, int m0, int n0)
{
    uint4* As = (uint4*)smem;               // 2048 slots (32KB)
    uint4* Bs = (uint4*)(smem + 32768);     // 2048 slots (32KB)
    float* red = (float*)smem;              // overlays As after sync
    const int tid = threadIdx.x;

    #pragma unroll
    for (int j = 0; j < 8; ++j) {
        const int S = tid + 256 * j;
        const int i = S >> 6, ln = S & 63;
        const int row  = (i & 1) * 16 + (ln & 15);
        const int col8 = (i >> 1) * 4 + (ln >> 4);
        uint4 av;
        if (MODE == 0) {
            const float* ap = Af + (size_t)(m0 + row) * 512 + col8 * 8;
            av = pack8(*(const float4*)ap, *(const float4*)(ap + 4));
        } else {
            av = *(const uint4*)(Ab + (size_t)(m0 + row) * 512 + col8 * 8);
        }
        const float* bp = Bf + (size_t)(n0 + row) * 512 + col8 * 8;
        As[S] = av;
        Bs[S] = pack8(*(const float4*)bp, *(const float4*)(bp + 4));
    }
    __syncthreads();

    const int w = tid >> 6, ln = tid & 63;
    f32x4 acc[4];                            // fo = tm*2+tn
    #pragma unroll
    for (int fo = 0; fo < 4; ++fo) acc[fo] = (f32x4){0.f,0.f,0.f,0.f};
    #pragma unroll
    for (int sl = 0; sl < 4; ++sl) {
        const int s = 4 * w + sl;
        const short8 a0 = *(const short8*)&As[(2*s+0)*64 + ln];
        const short8 a1 = *(const short8*)&As[(2*s+1)*64 + ln];
        const short8 b0 = *(const short8*)&Bs[(2*s+0)*64 + ln];
        const short8 b1 = *(const short8*)&Bs[(2*s+1)*64 + ln];
        acc[0] = __builtin_amdgcn_mfma_f32_16x16x32_bf16(a0, b0, acc[0], 0, 0, 0);
        acc[1] = __builtin_amdgcn_mfma_f32_16x16x32_bf16(a0, b1, acc[1], 0, 0, 0);
        acc[2] = __builtin_amdgcn_mfma_f32_16x16x32_bf16(a1, b0, acc[2], 0, 0, 0);
        acc[3] = __builtin_amdgcn_mfma_f32_16x16x32_bf16(a1, b1, acc[3], 0, 0, 0);
    }
    __syncthreads();                         // done reading As/Bs
    #pragma unroll
    for (int fo = 0; fo < 4; ++fo)
        #pragma unroll
        for (int r = 0; r < 4; ++r)
            red[w*1024 + fo*256 + r*64 + ln] = acc[fo][r];
    __syncthreads();
    #pragma unroll
    for (int j = 0; j < 4; ++j) {
        const int o = tid + 256 * j;
        float v = red[o] + red[1024 + o] + red[2048 + o] + red[3072 + o];
        const int fo = o >> 8, r = (o >> 6) & 3, l2 = o & 63;
        // C/D layout: col = lane&15, row = (lane>>4)*4 + reg [m89-verified]
        const int m = m0 + (fo >> 1) * 16 + ((l2 >> 4) << 2) + r;
        const int n = n0 + (fo & 1) * 16 + (l2 & 15);
        v += bias[n];
        if (MODE == 1) v *= hmul[(size_t)m * 512 + n];
        C[(size_t)m * 512 + n] = v;
    }
}

// ---- mid body: block (b, s) owns l0=2s, l0+1; online softmax over 13 chunks ----
__device__ __forceinline__ void mid_body(
    const float* __restrict__ maps, const float* __restrict__ hlin,
    const float* __restrict__ W_rect, const float* __restrict__ b_rect,
    float* __restrict__ attn_out, unsigned int* __restrict__ ctx_out,
    char* smem, int b, int s)
{
    float* h0    = (float*)smem;                   // 512
    float* h1    = h0 + 512;
    float* wv    = h0 + 1024;                      // 512  (6 KB)
    float* ftile = h0 + 1536;                      // 16*516 (33 KB)
    float* sraw  = ftile + 16 * 516;               // 2*208
    float* ep    = sraw + 2 * 208;                 // 2*16
    float* bc    = ep + 32;                        // 4

    const int l0 = 2 * s;
    const int tid = threadIdx.x;
    const int pi = tid >> 4, k = tid & 15;

    {
        const float4* H0 = (const float4*)(hlin + ((size_t)b * 32 + l0) * 512);
        const float4* H1 = (const float4*)(hlin + ((size_t)b * 32 + l0 + 1) * 512);
        const float4* WV = (const float4*)W_rect;
        if (tid < 128) { ((float4*)h0)[tid] = H0[tid]; ((float4*)wv)[tid] = WV[tid]; }
        else           { ((float4*)h1)[tid - 128] = H1[tid - 128]; }
    }
    __syncthreads();

    int aoff[8];
    float4 h0r[8], h1r[8], wr[8];
    #pragma unroll
    for (int j = 0; j < 8; ++j) {
        aoff[j] = k * 32 + ((j + k) & 7) * 4;
        h0r[j] = *(const float4*)&h0[aoff[j]];
        h1r[j] = *(const float4*)&h1[aoff[j]];
        wr[j]  = *(const float4*)&wv[aoff[j]];
    }

    const float* mb = maps + (size_t)b * 196 * 512;
    const float br = b_rect[0];
    const int d0 = tid * 2;

    float m0 = -INFINITY, m1 = -INFINITY, ls0 = 0.f, ls1 = 0.f;
    float cA0 = 0.f, cA1 = 0.f, cB0 = 0.f, cB1 = 0.f;

    for (int c = 0; c < 13; ++c) {
        __syncthreads();                           // ftile reuse safety
        #pragma unroll
        for (int it = 0; it < 8; ++it) {
            const int idx = tid + 256 * it;        // 0..2047 float4
            const int r = idx >> 7, c4 = idx & 127;
            int p = c * 16 + r; if (p > 195) p = 195;
            *(float4*)&ftile[r * 516 + c4 * 4] = *(const float4*)(mb + (size_t)p * 512 + c4 * 4);
        }
        __syncthreads();

        // score partials; butterfly-reduce over k (16-lane groups)
        float s0 = 0.f, s1 = 0.f;
        #pragma unroll
        for (int j = 0; j < 8; ++j) {
            const float4 f = *(const float4*)&ftile[pi * 516 + aoff[j]];
            const float4 A = h0r[j], Bv = h1r[j], W = wr[j];
            s0 += fmaxf(f.x + A.x, 0.f) * W.x + fmaxf(f.y + A.y, 0.f) * W.y
                + fmaxf(f.z + A.z, 0.f) * W.z + fmaxf(f.w + A.w, 0.f) * W.w;
            s1 += fmaxf(f.x + Bv.x, 0.f) * W.x + fmaxf(f.y + Bv.y, 0.f) * W.y
                + fmaxf(f.z + Bv.z, 0.f) * W.z + fmaxf(f.w + Bv.w, 0.f) * W.w;
        }
        #pragma unroll
        for (int msk = 1; msk <= 8; msk <<= 1) {
            s0 += __shfl_xor(s0, msk);
            s1 += __shfl_xor(s1, msk);
        }
        if (k == 0) {
            const int p = c * 16 + pi;
            const bool ok = (p <= 195);
            sraw[p]       = ok ? (s0 + br) : -INFINITY;
            sraw[208 + p] = ok ? (s1 + br) : -INFINITY;
        }
        __syncthreads();

        // lanes 0..31: l = tid>>4, pl = tid&15 -> max, exp, sum in one stage
        if (tid < 32) {
            const int l = tid >> 4, pl = tid & 15;
            const float sc = sraw[l * 208 + c * 16 + pl];
            float mx = sc;
            #pragma unroll
            for (int msk = 1; msk <= 8; msk <<= 1) mx = fmaxf(mx, __shfl_xor(mx, msk));
            const float nm = fmaxf(l ? m1 : m0, mx);
            const float e = (sc == -INFINITY) ? 0.f : __expf(sc - nm);
            ep[l * 16 + pl] = e;
            float es = e;
            #pragma unroll
            for (int msk = 1; msk <= 8; msk <<= 1) es += __shfl_xor(es, msk);
            if (pl == 0) { bc[l] = mx; bc[2 + l] = es; }
        }
        __syncthreads();

        const float nm0 = fmaxf(m0, bc[0]), nm1 = fmaxf(m1, bc[1]);
        const float al0 = __expf(m0 - nm0), al1 = __expf(m1 - nm1);
        ls0 = ls0 * al0 + bc[2];
        ls1 = ls1 * al1 + bc[3];
        m0 = nm0; m1 = nm1;
        cA0 *= al0; cA1 *= al0; cB0 *= al1; cB1 *= al1;
        #pragma unroll
        for (int r = 0; r < 16; ++r) {
            const float2 f = *(const float2*)&ftile[r * 516 + d0];
            const float w0 = ep[r], w1 = ep[16 + r];
            cA0 += w0 * f.x; cA1 += w0 * f.y;
            cB0 += w1 * f.x; cB1 += w1 * f.y;
        }
    }

    const float inv0 = 1.f / ls0, inv1 = 1.f / ls1;
    ctx_out[((size_t)b * 32 + l0) * 256 + tid]     = pack2(cA0 * inv0, cA1 * inv0);
    ctx_out[((size_t)b * 32 + l0 + 1) * 256 + tid] = pack2(cB0 * inv1, cB1 * inv1);
    for (int idx = tid; idx < 392; idx += 256) {
        const int l = idx & 1, p = idx >> 1;
        const float sc = sraw[l * 208 + p];
        attn_out[((size_t)b * 32 + l0 + l) * 196 + p] =
            __expf(sc - (l ? m1 : m0)) * (l ? inv1 : inv0);
    }
}

__global__ __launch_bounds__(256) void coatt_combo_kernel(
    const float* __restrict__ maps, const float* __restrict__ hiddens,
    const float* __restrict__ W_hidden, const float* __restrict__ b_hidden,
    const float* __restrict__ W_rect, const float* __restrict__ b_rect,
    const float* __restrict__ W_co, const float* __restrict__ b_co,
    float* __restrict__ out_co, float* __restrict__ out_attn,
    unsigned int* __restrict__ ctx32, int* __restrict__ flag1,
    int* __restrict__ flag2)
{
    __shared__ __align__(16) char smem[65536];
    const int bx = blockIdx.x;

    if (bx < 256) {
        // gemm1: hlin tile -> out_co (temp); rows (bx>>4)*32 = batch rows
        gemm_body<0>(hiddens, (const unsigned short*)nullptr, W_hidden, b_hidden,
                     (const float*)nullptr, out_co, smem,
                     (bx >> 4) * 32, (bx & 15) * 32);
        signal1(flag1, bx);
    } else if (bx < 512) {
        const int bid2 = bx - 256, b = bid2 >> 4, s = bid2 & 15;
        wait16(flag1, b * 16);
        mid_body(maps, out_co, W_rect, b_rect, out_attn, ctx32, smem, b, s);
        signal1(flag2, bid2);
    } else {
        const int bid2 = bx - 512, b = bid2 >> 4;
        wait16(flag2, b * 16);
        gemm_body<1>((const float*)nullptr, (const unsigned short*)ctx32, W_co,
                     b_co, hiddens, out_co, smem,
                     (bid2 >> 4) * 32, (bid2 & 15) * 32);
    }
}

extern "C" void kernel_launch(void* const* d_in, const int* in_sizes, int n_in,
                              void* d_out, int out_size, void* d_ws, size_t ws_size,
                              hipStream_t stream)
{
    const float* maps     = (const float*)d_in[0];
    const float* hiddens  = (const float*)d_in[1];
    const float* W_hidden = (const float*)d_in[2];
    const float* b_hidden = (const float*)d_in[3];
    const float* W_rect   = (const float*)d_in[4];
    const float* b_rect   = (const float*)d_in[5];
    const float* W_co     = (const float*)d_in[6];
    const float* b_co     = (const float*)d_in[7];

    float* out_co   = (float*)d_out;                    // (512,512): hlin temp, then final
    float* out_attn = out_co + (size_t)512 * 512;       // (512,196)

    char* ws = (char*)d_ws;
    unsigned int* ctx32 = (unsigned int*)ws;            // (512,512) bf16 = 512 KB
    int* flag1 = (int*)(ws + (1 << 20));                // 256 x 64B = 16 KB
    int* flag2 = (int*)(ws + (1 << 20) + (64 << 10));   // 256 x 64B

    hipLaunchKernelGGL(coatt_combo_kernel, dim3(768), dim3(256), 0, stream,
                       maps, hiddens, W_hidden, b_hidden, W_rect, b_rect,
                       W_co, b_co, out_co, out_attn, ctx32, flag1, flag2);
}